// Round 1
// baseline (255.908 us; speedup 1.0000x reference)
//
#include <hip/hip_runtime.h>
#include <hip/hip_bf16.h>

// Child-Sum Tree-LSTM: N=8192 nodes, K=8 children, D_IN=512, H=512, fp32 in/out.
// Strategy: bf16 MFMA for all GEMM-shaped work, fp32 elementwise epilogues.

#define NN 8192
#define KCH 8
#define HH 512

typedef __attribute__((ext_vector_type(4))) float f32x4;
typedef __attribute__((ext_vector_type(8))) short short8;

__device__ inline unsigned short f2bf(float f) {
    union { float f; unsigned u; } v; v.f = f;
    unsigned r = v.u + 0x7FFFu + ((v.u >> 16) & 1u);
    return (unsigned short)(r >> 16);
}
__device__ inline float bf2f(unsigned short b) {
    union { unsigned u; float f; } v; v.u = ((unsigned)b) << 16;
    return v.f;
}
__device__ inline float sigm(float x) { return 1.f / (1.f + __expf(-x)); }
__device__ inline float tanh_pf(float x) { return 2.f / (1.f + __expf(-2.f * x)) - 1.f; }

// ---------------- prep kernels ----------------

// x (fp32) -> bf16, 8 elems/thread
__global__ void k_cvt(const float* __restrict__ in, unsigned short* __restrict__ outp) {
    int i = blockIdx.x * blockDim.x + threadIdx.x;
    float4 a = ((const float4*)in)[2 * i];
    float4 b = ((const float4*)in)[2 * i + 1];
    uint4 o;
    o.x = (unsigned)f2bf(a.x) | ((unsigned)f2bf(a.y) << 16);
    o.y = (unsigned)f2bf(a.z) | ((unsigned)f2bf(a.w) << 16);
    o.z = (unsigned)f2bf(b.x) | ((unsigned)f2bf(b.y) << 16);
    o.w = (unsigned)f2bf(b.z) | ((unsigned)f2bf(b.w) << 16);
    ((uint4*)outp)[i] = o;
}

// h_sum = sum_k child_h[n][k][:]  -> bf16
__global__ void k_hsum(const float* __restrict__ ch, unsigned short* __restrict__ hs) {
    int i = blockIdx.x * blockDim.x + threadIdx.x;   // n*128 + h4
    int n = i >> 7, h4 = i & 127;
    const float4* base = (const float4*)(ch + (size_t)n * KCH * HH) + h4;
    float4 s = base[0];
#pragma unroll
    for (int k = 1; k < KCH; ++k) {
        float4 v = base[(size_t)k * 128];
        s.x += v.x; s.y += v.y; s.z += v.z; s.w += v.w;
    }
    unsigned long long pk = (unsigned long long)f2bf(s.x)
        | ((unsigned long long)f2bf(s.y) << 16)
        | ((unsigned long long)f2bf(s.z) << 32)
        | ((unsigned long long)f2bf(s.w) << 48);
    *(unsigned long long*)&hs[(size_t)i * 4] = pk;
}

// transpose 512x512 fp32 weight -> bf16 WT[c][k] = W[k][c]
struct P8 { const float* p[8]; };
__global__ void k_transpose_w(P8 wsrc, unsigned short* __restrict__ out) {
    __shared__ float tile[32][33];
    const float* W = wsrc.p[blockIdx.z];
    unsigned short* O = out + (size_t)blockIdx.z * 262144;
    int k0 = blockIdx.x * 32, c0 = blockIdx.y * 32;
    for (int r = threadIdx.y; r < 32; r += 8)
        tile[r][threadIdx.x] = W[(size_t)(k0 + r) * 512 + c0 + threadIdx.x];
    __syncthreads();
    for (int r = threadIdx.y; r < 32; r += 8)
        O[(size_t)(c0 + r) * 512 + k0 + threadIdx.x] = f2bf(tile[threadIdx.x][r]);
}

// ---------------- GEMM helpers ----------------

// stage bf16 A tile [128][32] into LDS (stride 40)
__device__ inline void stage_a(unsigned short (*a_lds)[40], const unsigned short* A,
                               int r0, int k0, int t) {
#pragma unroll
    for (int p = 0; p < 2; ++p) {
        int li = p * 256 + t;
        int row = li >> 2, c8 = (li & 3) * 8;
        *(uint4*)&a_lds[row][c8] = *(const uint4*)&A[(size_t)(r0 + row) * 512 + k0 + c8];
    }
}
// stage bf16 B^T tile [64][32] into LDS
__device__ inline void stage_b64(unsigned short (*b_lds)[40], const unsigned short* BT,
                                 int c0, int k0, int t) {
    int col = t >> 2, c8 = (t & 3) * 8;
    *(uint4*)&b_lds[col][c8] = *(const uint4*)&BT[(size_t)(c0 + col) * 512 + k0 + c8];
}

__device__ inline void gate_mfma(f32x4 (&acc)[4][2], const short8 (&af)[4],
                                 const unsigned short (*bl)[40], int bcol, int koff) {
    short8 b0 = *(const short8*)&bl[bcol][koff];
    short8 b1 = *(const short8*)&bl[bcol + 16][koff];
#pragma unroll
    for (int m = 0; m < 4; ++m) {
        acc[m][0] = __builtin_amdgcn_mfma_f32_16x16x32_bf16(af[m], b0, acc[m][0], 0, 0, 0);
        acc[m][1] = __builtin_amdgcn_mfma_f32_16x16x32_bf16(af[m], b1, acc[m][1], 0, 0, 0);
    }
}

// ---------------- gates kernel: i,o,u activations + x@Wf ----------------
// BM=128, BN=64, BK=32, 256 threads = 4 waves (2x2), wave tile 64x32.
__global__ __launch_bounds__(256) void k_gates(
    const unsigned short* __restrict__ xb,
    const unsigned short* __restrict__ hsb,
    const unsigned short* __restrict__ wT,   // [8][512][512]: Wi,Ui,Wf,Wo,Uo,Wu,Uu,Uf
    const float* __restrict__ bWi, const float* __restrict__ bUi,
    const float* __restrict__ bWf,
    const float* __restrict__ bWo, const float* __restrict__ bUo,
    const float* __restrict__ bWu, const float* __restrict__ bUu,
    unsigned short* __restrict__ Pq,   // i*u (bf16)
    unsigned short* __restrict__ Oq,   // sigmoid(o) (bf16)
    unsigned short* __restrict__ Fq)   // x@Wf + bWf (bf16)
{
    __shared__ unsigned short a_lds[128][40];
    __shared__ unsigned short b_lds[4][64][40];
    const int t = threadIdx.x, lane = t & 63, wid = t >> 6;
    const int wr = wid >> 1, wc = wid & 1;
    const int r0 = blockIdx.y * 128, c0 = blockIdx.x * 64;

    f32x4 acc_i[4][2] = {}; f32x4 acc_f[4][2] = {};
    f32x4 acc_o[4][2] = {}; f32x4 acc_u[4][2] = {};

    const int koff = (lane >> 4) * 8;
    const int arow = wr * 64 + (lane & 15);
    const int bcol = wc * 32 + (lane & 15);

    // phase 0: x @ {Wi, Wf, Wo, Wu}
    for (int kq = 0; kq < 512; kq += 32) {
        __syncthreads();
        stage_a(a_lds, xb, r0, kq, t);
        stage_b64(b_lds[0], wT + (size_t)0 * 262144, c0, kq, t);
        stage_b64(b_lds[1], wT + (size_t)2 * 262144, c0, kq, t);
        stage_b64(b_lds[2], wT + (size_t)3 * 262144, c0, kq, t);
        stage_b64(b_lds[3], wT + (size_t)5 * 262144, c0, kq, t);
        __syncthreads();
        short8 af[4];
#pragma unroll
        for (int m = 0; m < 4; ++m) af[m] = *(const short8*)&a_lds[arow + m * 16][koff];
        gate_mfma(acc_i, af, b_lds[0], bcol, koff);
        gate_mfma(acc_f, af, b_lds[1], bcol, koff);
        gate_mfma(acc_o, af, b_lds[2], bcol, koff);
        gate_mfma(acc_u, af, b_lds[3], bcol, koff);
    }
    // phase 1: h_sum @ {Ui, Uo, Uu}
    for (int kq = 0; kq < 512; kq += 32) {
        __syncthreads();
        stage_a(a_lds, hsb, r0, kq, t);
        stage_b64(b_lds[0], wT + (size_t)1 * 262144, c0, kq, t);
        stage_b64(b_lds[1], wT + (size_t)4 * 262144, c0, kq, t);
        stage_b64(b_lds[2], wT + (size_t)6 * 262144, c0, kq, t);
        __syncthreads();
        short8 af[4];
#pragma unroll
        for (int m = 0; m < 4; ++m) af[m] = *(const short8*)&a_lds[arow + m * 16][koff];
        gate_mfma(acc_i, af, b_lds[0], bcol, koff);
        gate_mfma(acc_o, af, b_lds[1], bcol, koff);
        gate_mfma(acc_u, af, b_lds[2], bcol, koff);
    }
    // epilogue
#pragma unroll
    for (int m = 0; m < 4; ++m) {
#pragma unroll
        for (int n = 0; n < 2; ++n) {
            int col = c0 + wc * 32 + n * 16 + (lane & 15);
            float bi = bWi[col] + bUi[col];
            float bf = bWf[col];
            float bo = bWo[col] + bUo[col];
            float bu = bWu[col] + bUu[col];
#pragma unroll
            for (int r = 0; r < 4; ++r) {
                int row = r0 + wr * 64 + m * 16 + (lane >> 4) * 4 + r;
                size_t idx = (size_t)row * 512 + col;
                float vi = sigm(acc_i[m][n][r] + bi);
                float vu = tanh_pf(acc_u[m][n][r] + bu);
                Pq[idx] = f2bf(vi * vu);
                Oq[idx] = f2bf(sigm(acc_o[m][n][r] + bo));
                Fq[idx] = f2bf(acc_f[m][n][r] + bf);
            }
        }
    }
}

// ---------------- f-einsum + combine kernel ----------------
// rows = child index r = n*8+k (65536 rows). BM=128 (16 nodes), BN=128, BK=32.
// 4 waves (2x2), wave tile 64x64.
__global__ __launch_bounds__(256) void k_fc(
    const float* __restrict__ ch,            // child_h [65536][512] fp32
    const float* __restrict__ cc,            // child_c
    const unsigned short* __restrict__ ufT,  // Uf^T bf16 [512][512]
    const float* __restrict__ bUf,
    const unsigned short* __restrict__ Pq,
    const unsigned short* __restrict__ Oq,
    const unsigned short* __restrict__ Fq,
    float* __restrict__ out)                 // [2][8192][512]
{
    __shared__ union LdsU {
        struct { unsigned short a[128][40]; unsigned short b[128][40]; } s;
        float f[128][128];
    } u;
    const int t = threadIdx.x, lane = t & 63, wid = t >> 6;
    const int wr = wid >> 1, wc = wid & 1;
    const int r0 = blockIdx.y * 128, c0 = blockIdx.x * 128;

    f32x4 acc[4][4] = {};
    const int koff = (lane >> 4) * 8;
    const int arow = wr * 64 + (lane & 15);
    const int bcol = wc * 64 + (lane & 15);

    for (int kq = 0; kq < 512; kq += 32) {
        __syncthreads();
        // stage A: child_h fp32 -> bf16, 128x32
#pragma unroll
        for (int p = 0; p < 4; ++p) {
            int li = p * 256 + t;
            int row = li >> 3, c4 = (li & 7) * 4;
            float4 v = *(const float4*)&ch[(size_t)(r0 + row) * 512 + kq + c4];
            unsigned long long pk = (unsigned long long)f2bf(v.x)
                | ((unsigned long long)f2bf(v.y) << 16)
                | ((unsigned long long)f2bf(v.z) << 32)
                | ((unsigned long long)f2bf(v.w) << 48);
            *(unsigned long long*)&u.s.a[row][c4] = pk;
        }
        // stage B: Uf^T, 128 cols x 32 k
#pragma unroll
        for (int p = 0; p < 2; ++p) {
            int li = p * 256 + t;
            int col = li >> 2, c8 = (li & 3) * 8;
            *(uint4*)&u.s.b[col][c8] = *(const uint4*)&ufT[(size_t)(c0 + col) * 512 + kq + c8];
        }
        __syncthreads();
        short8 af[4], bfr[4];
#pragma unroll
        for (int m = 0; m < 4; ++m) af[m] = *(const short8*)&u.s.a[arow + m * 16][koff];
#pragma unroll
        for (int n = 0; n < 4; ++n) bfr[n] = *(const short8*)&u.s.b[bcol + n * 16][koff];
#pragma unroll
        for (int m = 0; m < 4; ++m)
#pragma unroll
            for (int n = 0; n < 4; ++n)
                acc[m][n] = __builtin_amdgcn_mfma_f32_16x16x32_bf16(af[m], bfr[n], acc[m][n], 0, 0, 0);
    }
    __syncthreads();
    // acc -> f_lds (overwrites staging buffers; all MFMA reads done)
#pragma unroll
    for (int m = 0; m < 4; ++m)
#pragma unroll
        for (int n = 0; n < 4; ++n)
#pragma unroll
            for (int r = 0; r < 4; ++r)
                u.f[wr * 64 + m * 16 + (lane >> 4) * 4 + r][wc * 64 + n * 16 + (lane & 15)] = acc[m][n][r];
    __syncthreads();
    // combine: per node (8 consecutive rows), per column
    const int j = t & 127, q = t >> 7;   // q in {0,1}
    for (int ni = q; ni < 16; ni += 2) {
        int node = (r0 >> 3) + ni;
        int col = c0 + j;
        size_t nidx = (size_t)node * 512 + col;
        float xf = bf2f(Fq[nidx]) + bUf[col];
        float fc = 0.f;
#pragma unroll
        for (int k = 0; k < 8; ++k) {
            float pre = u.f[ni * 8 + k][j] + xf;
            float fg = sigm(pre);
            fc += fg * cc[(size_t)(r0 + ni * 8 + k) * 512 + col];
        }
        float cval = bf2f(Pq[nidx]) + fc;
        float h = bf2f(Oq[nidx]) * tanh_pf(cval);
        out[nidx] = h;
        out[(size_t)NN * HH + nidx] = cval;
    }
}

// ---------------- launch ----------------
extern "C" void kernel_launch(void* const* d_in, const int* in_sizes, int n_in,
                              void* d_out, int out_size, void* d_ws, size_t ws_size,
                              hipStream_t stream) {
    const float* x   = (const float*)d_in[0];
    const float* ch  = (const float*)d_in[1];
    const float* cc  = (const float*)d_in[2];
    const float* Wi  = (const float*)d_in[3];  const float* bWi = (const float*)d_in[4];
    const float* Ui  = (const float*)d_in[5];  const float* bUi = (const float*)d_in[6];
    const float* Wf  = (const float*)d_in[7];  const float* bWf = (const float*)d_in[8];
    const float* Uf  = (const float*)d_in[9];  const float* bUf = (const float*)d_in[10];
    const float* Wo  = (const float*)d_in[11]; const float* bWo = (const float*)d_in[12];
    const float* Uo  = (const float*)d_in[13]; const float* bUo = (const float*)d_in[14];
    const float* Wu  = (const float*)d_in[15]; const float* bWu = (const float*)d_in[16];
    const float* Uu  = (const float*)d_in[17]; const float* bUu = (const float*)d_in[18];
    float* out = (float*)d_out;

    unsigned short* xb  = (unsigned short*)d_ws;                 // 8192*512
    unsigned short* hsb = xb  + (size_t)NN * HH;                 // 8192*512
    unsigned short* wT  = hsb + (size_t)NN * HH;                 // 8*512*512
    unsigned short* Pq  = wT  + (size_t)8 * 262144;
    unsigned short* Oq  = Pq  + (size_t)NN * HH;
    unsigned short* Fq  = Oq  + (size_t)NN * HH;

    k_cvt<<<(NN * HH / 8) / 256, 256, 0, stream>>>(x, xb);
    k_hsum<<<(NN * 128) / 256, 256, 0, stream>>>(ch, hsb);
    P8 wp;
    wp.p[0] = Wi; wp.p[1] = Ui; wp.p[2] = Wf; wp.p[3] = Wo;
    wp.p[4] = Uo; wp.p[5] = Wu; wp.p[6] = Uu; wp.p[7] = Uf;
    k_transpose_w<<<dim3(16, 16, 8), dim3(32, 8), 0, stream>>>(wp, wT);
    k_gates<<<dim3(8, 64), 256, 0, stream>>>(xb, hsb, wT,
                                             bWi, bUi, bWf, bWo, bUo, bWu, bUu,
                                             Pq, Oq, Fq);
    k_fc<<<dim3(4, 512), 256, 0, stream>>>(ch, cc, wT + (size_t)7 * 262144, bUf,
                                           Pq, Oq, Fq, out);
}